// Round 7
// baseline (41.398 us; speedup 1.0000x reference)
//
#include <hip/hip_runtime.h>

#define NCH 8
#define CACHE 8   // float4 per lane -> covers segments up to 256 points per frustum

__device__ __forceinline__ void acc4(const float4& v, float4& sum, float4& sq, float4& mx) {
    sum.x += v.x; sq.x += v.x * v.x; mx.x = fmaxf(mx.x, v.x);
    sum.y += v.y; sq.y += v.y * v.y; mx.y = fmaxf(mx.y, v.y);
    sum.z += v.z; sq.z += v.z * v.z; mx.z = fmaxf(mx.z, v.z);
    sum.w += v.w; sq.w += v.w * v.w; mx.w = fmaxf(mx.w, v.w);
}

__device__ __forceinline__ float4 norm4(const float4& v, const float4& m, const float4& d) {
    float4 o;
    o.x = (v.x - m.x) * d.x;
    o.y = (v.y - m.y) * d.y;
    o.z = (v.z - m.z) * d.z;
    o.w = (v.w - m.w) * d.w;
    return o;
}

// Fully fused: one WAVE per frustum (i_frustum sorted, i_inv identity -> contiguous
// slices). Each wave binary-searches its segment start itself (all lanes redundantly,
// wave-uniform address -> broadcast loads, hidden under other waves' streaming); the
// segment end is start + counts[f]. Single pass: register-cached load, shuffle reduce,
// redundant per-lane stats, normalize from the cache. No LDS, no barriers, 1 dispatch.
__global__ __launch_bounds__(256) void k_fused(
    const float* __restrict__ pc, const int* __restrict__ i_frustum,
    const float* __restrict__ counts, int n, int F,
    float* __restrict__ out_mean, float* __restrict__ out_std,
    float* __restrict__ out_max, float* __restrict__ out_pcn)
{
    const int wid = (blockIdx.x * blockDim.x + threadIdx.x) >> 6;  // global wave id
    if (wid >= F) return;                                          // wave-uniform exit
    const int lane = threadIdx.x & 63;

    // Segment start via binary search (all lanes same key: no divergence, broadcast loads).
    int lo = 0, hi = n;
    while (lo < hi) {
        int mid = (lo + hi) >> 1;
        if (i_frustum[mid] < wid) lo = mid + 1; else hi = mid;
    }
    const float cnt = counts[wid];
    const int s = lo;
    const int e = s + (int)cnt;   // counts are small integers, exact in float

    const float4* __restrict__ pc4 = reinterpret_cast<const float4*>(pc);
    float4* __restrict__ out4 = reinterpret_cast<float4*>(out_pcn);

    const int b = s * 2, E = e * 2;   // float4-granular range (NCH=8 -> 2 float4/point)

    float4 sum = {0.f, 0.f, 0.f, 0.f};
    float4 sq  = {0.f, 0.f, 0.f, 0.f};
    float4 mx  = {0.f, 0.f, 0.f, 0.f};  // 0-init == scatter-max onto zeros (include_self)
    float4 c[CACHE];

    int k = b + lane;
    #pragma unroll
    for (int u = 0; u < CACHE; ++u) {
        if (k < E) { c[u] = pc4[k]; acc4(c[u], sum, sq, mx); }
        k += 64;
    }
    for (int kk = k; kk < E; kk += 64) { float4 v = pc4[kk]; acc4(v, sum, sq, mx); }  // rare

    // Lane parity p = lane&1 owns channels [4p, 4p+4). Reduce lanes differing in bits 1..5.
    #pragma unroll
    for (int m = 2; m <= 32; m <<= 1) {
        sum.x += __shfl_xor(sum.x, m, 64);
        sum.y += __shfl_xor(sum.y, m, 64);
        sum.z += __shfl_xor(sum.z, m, 64);
        sum.w += __shfl_xor(sum.w, m, 64);
        sq.x  += __shfl_xor(sq.x,  m, 64);
        sq.y  += __shfl_xor(sq.y,  m, 64);
        sq.z  += __shfl_xor(sq.z,  m, 64);
        sq.w  += __shfl_xor(sq.w,  m, 64);
        mx.x = fmaxf(mx.x, __shfl_xor(mx.x, m, 64));
        mx.y = fmaxf(mx.y, __shfl_xor(mx.y, m, 64));
        mx.z = fmaxf(mx.z, __shfl_xor(mx.z, m, 64));
        mx.w = fmaxf(mx.w, __shfl_xor(mx.w, m, 64));
    }

    // Every lane holds its parity-group totals; compute stats redundantly (cheap).
    const float invc = 1.0f / fmaxf(cnt, 1.0f);
    float4 mean, sd, dv;
    mean.x = sum.x * invc; mean.y = sum.y * invc; mean.z = sum.z * invc; mean.w = sum.w * invc;
    float vx = fmaxf(sq.x * invc - mean.x * mean.x, 0.0f);
    float vy = fmaxf(sq.y * invc - mean.y * mean.y, 0.0f);
    float vz = fmaxf(sq.z * invc - mean.z * mean.z, 0.0f);
    float vw = fmaxf(sq.w * invc - mean.w * mean.w, 0.0f);
    sd.x = sqrtf(vx); sd.y = sqrtf(vy); sd.z = sqrtf(vz); sd.w = sqrtf(vw);
    dv.x = 1.0f / (sd.x > 0.f ? sd.x : 1.f);
    dv.y = 1.0f / (sd.y > 0.f ? sd.y : 1.f);
    dv.z = 1.0f / (sd.z > 0.f ? sd.z : 1.f);
    dv.w = 1.0f / (sd.w > 0.f ? sd.w : 1.f);

    if (lane < 2) {  // lane 0 -> channels 0-3, lane 1 -> channels 4-7
        reinterpret_cast<float4*>(out_mean + (size_t)wid * NCH)[lane] = mean;
        reinterpret_cast<float4*>(out_std  + (size_t)wid * NCH)[lane] = sd;
        reinterpret_cast<float4*>(out_max  + (size_t)wid * NCH)[lane] = mx;
    }

    // Normalize from the register cache (single HBM read of pc).
    k = b + lane;
    #pragma unroll
    for (int u = 0; u < CACHE; ++u) {
        if (k < E) out4[k] = norm4(c[u], mean, dv);
        k += 64;
    }
    for (int kk = k; kk < E; kk += 64) out4[kk] = norm4(pc4[kk], mean, dv);  // rare
}

extern "C" void kernel_launch(void* const* d_in, const int* in_sizes, int n_in,
                              void* d_out, int out_size, void* d_ws, size_t ws_size,
                              hipStream_t stream) {
    const float* pc        = (const float*)d_in[0];
    const int*   i_frustum = (const int*)d_in[1];
    const float* counts    = (const float*)d_in[3];

    int n = in_sizes[0] / NCH;   // 2,000,000 points
    int F = in_sizes[3];         // 14,400 frustums

    float* out_mean = (float*)d_out;
    float* out_std  = out_mean + (size_t)F * NCH;
    float* out_max  = out_std  + (size_t)F * NCH;
    float* out_pcn  = out_max  + (size_t)F * NCH;

    int waves_per_block = 256 / 64;
    int blocks = (F + waves_per_block - 1) / waves_per_block;
    k_fused<<<blocks, 256, 0, stream>>>(pc, i_frustum, counts, n, F,
                                        out_mean, out_std, out_max, out_pcn);
}

// Round 9
// 34.700 us; speedup vs baseline: 1.1930x; 1.1930x over previous
//
#include <hip/hip_runtime.h>

#define NCH 8
#define CACHE 8   // float4 per lane -> covers segments up to 256 points per frustum

typedef float v4f __attribute__((ext_vector_type(4)));

__device__ __forceinline__ int lower_bound_i32(const int* __restrict__ a, int n, int key) {
    int lo = 0, hi = n;
    while (lo < hi) {
        int mid = (lo + hi) >> 1;
        if (a[mid] < key) lo = mid + 1; else hi = mid;
    }
    return lo;
}

// Kernel S: per-frustum start offsets via parallel binary search over sorted i_frustum.
// 14400 independent threads -> 225 waves, latency hidden by thread parallelism.
__global__ __launch_bounds__(256) void k_starts(const int* __restrict__ i_frustum, int n, int F,
                                                int* __restrict__ starts) {
    int t = blockIdx.x * blockDim.x + threadIdx.x;
    if (t <= F) starts[t] = lower_bound_i32(i_frustum, n, t);
}

__device__ __forceinline__ void acc4(const float4& v, float4& sum, float4& sq, float4& mx) {
    sum.x += v.x; sq.x += v.x * v.x; mx.x = fmaxf(mx.x, v.x);
    sum.y += v.y; sq.y += v.y * v.y; mx.y = fmaxf(mx.y, v.y);
    sum.z += v.z; sq.z += v.z * v.z; mx.z = fmaxf(mx.z, v.z);
    sum.w += v.w; sq.w += v.w * v.w; mx.w = fmaxf(mx.w, v.w);
}

__device__ __forceinline__ v4f norm4(const float4& v, const float4& m, const float4& d) {
    v4f o;
    o.x = (v.x - m.x) * d.x;
    o.y = (v.y - m.y) * d.y;
    o.z = (v.z - m.z) * d.z;
    o.w = (v.w - m.w) * d.w;
    return o;
}

// One WAVE per frustum (i_frustum sorted, i_inv identity -> contiguous slices).
// Single pass: segment cached in registers, wave shuffle reduce (no LDS/barriers),
// redundant per-lane stats, normalize from the register cache, non-temporal output
// stores (output never re-read; keeps pc L3-resident).
__global__ __launch_bounds__(128) void k_wave(
    const float* __restrict__ pc, const float* __restrict__ counts,
    const int* __restrict__ starts, int F,
    float* __restrict__ out_mean, float* __restrict__ out_std,
    float* __restrict__ out_max, float* __restrict__ out_pcn)
{
    const int wid = (blockIdx.x * blockDim.x + threadIdx.x) >> 6;  // global wave id
    if (wid >= F) return;                                          // wave-uniform exit
    const int lane = threadIdx.x & 63;

    const int s = starts[wid];
    const int e = starts[wid + 1];   // adjacent scalar loads, single fetch
    const float4* __restrict__ pc4 = reinterpret_cast<const float4*>(pc);
    v4f* __restrict__ out4 = reinterpret_cast<v4f*>(out_pcn);

    const int b = s * 2, E = e * 2;   // float4-granular range (NCH=8 -> 2 float4/point)

    float4 sum = {0.f, 0.f, 0.f, 0.f};
    float4 sq  = {0.f, 0.f, 0.f, 0.f};
    float4 mx  = {0.f, 0.f, 0.f, 0.f};  // 0-init == scatter-max onto zeros (include_self)
    float4 c[CACHE];

    int k = b + lane;
    #pragma unroll
    for (int u = 0; u < CACHE; ++u) {
        if (k < E) { c[u] = pc4[k]; acc4(c[u], sum, sq, mx); }
        k += 64;
    }
    for (int kk = k; kk < E; kk += 64) { float4 v = pc4[kk]; acc4(v, sum, sq, mx); }  // rare

    // Lane parity p = lane&1 owns channels [4p, 4p+4). Reduce lanes differing in bits 1..5.
    #pragma unroll
    for (int m = 2; m <= 32; m <<= 1) {
        sum.x += __shfl_xor(sum.x, m, 64);
        sum.y += __shfl_xor(sum.y, m, 64);
        sum.z += __shfl_xor(sum.z, m, 64);
        sum.w += __shfl_xor(sum.w, m, 64);
        sq.x  += __shfl_xor(sq.x,  m, 64);
        sq.y  += __shfl_xor(sq.y,  m, 64);
        sq.z  += __shfl_xor(sq.z,  m, 64);
        sq.w  += __shfl_xor(sq.w,  m, 64);
        mx.x = fmaxf(mx.x, __shfl_xor(mx.x, m, 64));
        mx.y = fmaxf(mx.y, __shfl_xor(mx.y, m, 64));
        mx.z = fmaxf(mx.z, __shfl_xor(mx.z, m, 64));
        mx.w = fmaxf(mx.w, __shfl_xor(mx.w, m, 64));
    }

    // Every lane holds its parity-group totals; compute stats redundantly (cheap).
    const float cnt  = counts[wid];
    const float invc = 1.0f / fmaxf(cnt, 1.0f);
    float4 mean, sd, dv;
    mean.x = sum.x * invc; mean.y = sum.y * invc; mean.z = sum.z * invc; mean.w = sum.w * invc;
    float vx = fmaxf(sq.x * invc - mean.x * mean.x, 0.0f);
    float vy = fmaxf(sq.y * invc - mean.y * mean.y, 0.0f);
    float vz = fmaxf(sq.z * invc - mean.z * mean.z, 0.0f);
    float vw = fmaxf(sq.w * invc - mean.w * mean.w, 0.0f);
    sd.x = sqrtf(vx); sd.y = sqrtf(vy); sd.z = sqrtf(vz); sd.w = sqrtf(vw);
    dv.x = 1.0f / (sd.x > 0.f ? sd.x : 1.f);
    dv.y = 1.0f / (sd.y > 0.f ? sd.y : 1.f);
    dv.z = 1.0f / (sd.z > 0.f ? sd.z : 1.f);
    dv.w = 1.0f / (sd.w > 0.f ? sd.w : 1.f);

    if (lane < 2) {  // lane 0 -> channels 0-3, lane 1 -> channels 4-7
        reinterpret_cast<float4*>(out_mean + (size_t)wid * NCH)[lane] = mean;
        reinterpret_cast<float4*>(out_std  + (size_t)wid * NCH)[lane] = sd;
        reinterpret_cast<float4*>(out_max  + (size_t)wid * NCH)[lane] = mx;
    }

    // Normalize from the register cache; non-temporal stores (never re-read).
    k = b + lane;
    #pragma unroll
    for (int u = 0; u < CACHE; ++u) {
        if (k < E) {
            v4f o = norm4(c[u], mean, dv);
            __builtin_nontemporal_store(o, &out4[k]);
        }
        k += 64;
    }
    for (int kk = k; kk < E; kk += 64) {  // rare
        v4f o = norm4(pc4[kk], mean, dv);
        __builtin_nontemporal_store(o, &out4[kk]);
    }
}

extern "C" void kernel_launch(void* const* d_in, const int* in_sizes, int n_in,
                              void* d_out, int out_size, void* d_ws, size_t ws_size,
                              hipStream_t stream) {
    const float* pc        = (const float*)d_in[0];
    const int*   i_frustum = (const int*)d_in[1];
    const float* counts    = (const float*)d_in[3];

    int n = in_sizes[0] / NCH;   // 2,000,000 points
    int F = in_sizes[3];         // 14,400 frustums

    float* out_mean = (float*)d_out;
    float* out_std  = out_mean + (size_t)F * NCH;
    float* out_max  = out_std  + (size_t)F * NCH;
    float* out_pcn  = out_max  + (size_t)F * NCH;

    int* starts = (int*)d_ws;    // F+1 ints

    k_starts<<<(F + 1 + 255) / 256, 256, 0, stream>>>(i_frustum, n, F, starts);
    int waves_per_block = 128 / 64;
    int blocks = (F + waves_per_block - 1) / waves_per_block;
    k_wave<<<blocks, 128, 0, stream>>>(pc, counts, starts, F, out_mean, out_std, out_max, out_pcn);
}

// Round 10
// 31.498 us; speedup vs baseline: 1.3143x; 1.1017x over previous
//
#include <hip/hip_runtime.h>

#define NCH 8
#define CACHE 8   // float4 per lane -> covers segments up to 256 points per frustum

typedef float v4f __attribute__((ext_vector_type(4)));

__device__ __forceinline__ void acc4(const float4& v, float4& sum, float4& sq, float4& mx) {
    sum.x += v.x; sq.x += v.x * v.x; mx.x = fmaxf(mx.x, v.x);
    sum.y += v.y; sq.y += v.y * v.y; mx.y = fmaxf(mx.y, v.y);
    sum.z += v.z; sq.z += v.z * v.z; mx.z = fmaxf(mx.z, v.z);
    sum.w += v.w; sq.w += v.w * v.w; mx.w = fmaxf(mx.w, v.w);
}

__device__ __forceinline__ v4f norm4(const float4& v, const float4& m, const float4& d) {
    v4f o;
    o.x = (v.x - m.x) * d.x;
    o.y = (v.y - m.y) * d.y;
    o.z = (v.z - m.z) * d.z;
    o.w = (v.w - m.w) * d.w;
    return o;
}

// Wave-cooperative lower_bound: smallest idx with a[idx] >= key (a sorted, len-n array).
// Each round 64 lanes probe evenly spaced positions; ballot+popcount collapses the
// range 64x -> 4 dependent rounds for n=2M (vs 21 for scalar binary search).
__device__ __forceinline__ int wave_lower_bound(const int* __restrict__ a, int n, int key,
                                                int lane) {
    int lo = 0, len = n;
    while (len > 64) {
        int step = (len + 63) >> 6;                       // ceil(len/64)
        int p = lo + lane * step;
        int v = (p < lo + len) ? a[p] : 0x7fffffff;       // lo+len <= n invariant
        unsigned long long bal = __ballot(v < key);
        int cnt = __popcll(bal);                          // preds are a prefix (sorted)
        if (cnt == 0) return lo;                          // a[lo] >= key
        int nlo = lo + (cnt - 1) * step + 1;
        int nhi = lo + len;
        int cap = lo + cnt * step;
        if (cnt < 64 && cap < nhi) nhi = cap;
        lo = nlo; len = nhi - nlo;
    }
    // final round: probe lo..lo+len-1 directly
    int v = (lane < len) ? a[lo + lane] : 0x7fffffff;
    unsigned long long bal = __ballot(v < key);
    return lo + __popcll(bal);
}

// Single fused dispatch: one WAVE per frustum (i_frustum sorted, i_inv identity ->
// contiguous slices). Wave-cooperative 64-ary search finds the segment start; end =
// start + counts[f]. One streaming pass: load, shuffle reduce (no LDS/barriers),
// redundant per-lane stats, normalize (loads re-hit L1), non-temporal output stores.
__global__ __launch_bounds__(128) void k_fused(
    const float* __restrict__ pc, const int* __restrict__ i_frustum,
    const float* __restrict__ counts, int n, int F,
    float* __restrict__ out_mean, float* __restrict__ out_std,
    float* __restrict__ out_max, float* __restrict__ out_pcn)
{
    const int wid = (blockIdx.x * blockDim.x + threadIdx.x) >> 6;  // global wave id
    if (wid >= F) return;                                          // wave-uniform exit
    const int lane = threadIdx.x & 63;

    const int s = wave_lower_bound(i_frustum, n, wid, lane);
    const float cnt = counts[wid];
    const int e = s + (int)cnt;      // counts are small integers, exact in float

    const float4* __restrict__ pc4 = reinterpret_cast<const float4*>(pc);
    v4f* __restrict__ out4 = reinterpret_cast<v4f*>(out_pcn);

    const int b = s * 2, E = e * 2;  // float4-granular range (NCH=8 -> 2 float4/point)

    float4 sum = {0.f, 0.f, 0.f, 0.f};
    float4 sq  = {0.f, 0.f, 0.f, 0.f};
    float4 mx  = {0.f, 0.f, 0.f, 0.f};  // 0-init == scatter-max onto zeros (include_self)
    float4 c[CACHE];

    int k = b + lane;
    #pragma unroll
    for (int u = 0; u < CACHE; ++u) {
        if (k < E) { c[u] = pc4[k]; acc4(c[u], sum, sq, mx); }
        k += 64;
    }
    for (int kk = k; kk < E; kk += 64) { float4 v = pc4[kk]; acc4(v, sum, sq, mx); }  // rare

    // Lane parity p = lane&1 owns channels [4p, 4p+4). Reduce lanes differing in bits 1..5.
    #pragma unroll
    for (int m = 2; m <= 32; m <<= 1) {
        sum.x += __shfl_xor(sum.x, m, 64);
        sum.y += __shfl_xor(sum.y, m, 64);
        sum.z += __shfl_xor(sum.z, m, 64);
        sum.w += __shfl_xor(sum.w, m, 64);
        sq.x  += __shfl_xor(sq.x,  m, 64);
        sq.y  += __shfl_xor(sq.y,  m, 64);
        sq.z  += __shfl_xor(sq.z,  m, 64);
        sq.w  += __shfl_xor(sq.w,  m, 64);
        mx.x = fmaxf(mx.x, __shfl_xor(mx.x, m, 64));
        mx.y = fmaxf(mx.y, __shfl_xor(mx.y, m, 64));
        mx.z = fmaxf(mx.z, __shfl_xor(mx.z, m, 64));
        mx.w = fmaxf(mx.w, __shfl_xor(mx.w, m, 64));
    }

    // Every lane holds its parity-group totals; compute stats redundantly (cheap).
    const float invc = 1.0f / fmaxf(cnt, 1.0f);
    float4 mean, sd, dv;
    mean.x = sum.x * invc; mean.y = sum.y * invc; mean.z = sum.z * invc; mean.w = sum.w * invc;
    float vx = fmaxf(sq.x * invc - mean.x * mean.x, 0.0f);
    float vy = fmaxf(sq.y * invc - mean.y * mean.y, 0.0f);
    float vz = fmaxf(sq.z * invc - mean.z * mean.z, 0.0f);
    float vw = fmaxf(sq.w * invc - mean.w * mean.w, 0.0f);
    sd.x = sqrtf(vx); sd.y = sqrtf(vy); sd.z = sqrtf(vz); sd.w = sqrtf(vw);
    dv.x = 1.0f / (sd.x > 0.f ? sd.x : 1.f);
    dv.y = 1.0f / (sd.y > 0.f ? sd.y : 1.f);
    dv.z = 1.0f / (sd.z > 0.f ? sd.z : 1.f);
    dv.w = 1.0f / (sd.w > 0.f ? sd.w : 1.f);

    if (lane < 2) {  // lane 0 -> channels 0-3, lane 1 -> channels 4-7
        reinterpret_cast<float4*>(out_mean + (size_t)wid * NCH)[lane] = mean;
        reinterpret_cast<float4*>(out_std  + (size_t)wid * NCH)[lane] = sd;
        reinterpret_cast<float4*>(out_max  + (size_t)wid * NCH)[lane] = mx;
    }

    // Normalize from the cached values (compiler may re-load; hits L1); NT stores.
    k = b + lane;
    #pragma unroll
    for (int u = 0; u < CACHE; ++u) {
        if (k < E) {
            v4f o = norm4(c[u], mean, dv);
            __builtin_nontemporal_store(o, &out4[k]);
        }
        k += 64;
    }
    for (int kk = k; kk < E; kk += 64) {  // rare
        v4f o = norm4(pc4[kk], mean, dv);
        __builtin_nontemporal_store(o, &out4[kk]);
    }
}

extern "C" void kernel_launch(void* const* d_in, const int* in_sizes, int n_in,
                              void* d_out, int out_size, void* d_ws, size_t ws_size,
                              hipStream_t stream) {
    const float* pc        = (const float*)d_in[0];
    const int*   i_frustum = (const int*)d_in[1];
    const float* counts    = (const float*)d_in[3];

    int n = in_sizes[0] / NCH;   // 2,000,000 points
    int F = in_sizes[3];         // 14,400 frustums

    float* out_mean = (float*)d_out;
    float* out_std  = out_mean + (size_t)F * NCH;
    float* out_max  = out_std  + (size_t)F * NCH;
    float* out_pcn  = out_max  + (size_t)F * NCH;

    int waves_per_block = 128 / 64;
    int blocks = (F + waves_per_block - 1) / waves_per_block;
    k_fused<<<blocks, 128, 0, stream>>>(pc, i_frustum, counts, n, F,
                                        out_mean, out_std, out_max, out_pcn);
}